// Round 3
// baseline (120.046 us; speedup 1.0000x reference)
//
#include <hip/hip_runtime.h>
#include <hip/hip_fp16.h>
#include <math.h>

#define B_SZ 16
#define N_SZ 16384
#define T_FR 64       // frames per block
#define NTHR 256      // 4 waves
#define NBIN 65
#define NMEL 80
#define NCH  81
#define KN   6
#define MSTR 70       // mag LDS row stride in halves
#define BSTR 136      // B LDS row stride in halves (272 B pitch: 16B-aligned, bank-spread)

typedef _Float16 h8  __attribute__((ext_vector_type(8)));
typedef float    f4  __attribute__((ext_vector_type(4)));
static_assert(sizeof(h8) == 16, "h8 must be 4 VGPRs");

// ---------------- compile-time mel filterbank (host-side constexpr only) ----------------

constexpr double cln(double x) {
  int k = 0;
  while (x > 1.5)  { x *= 0.5; ++k; }
  while (x < 0.75) { x *= 2.0; --k; }
  const double y = (x - 1.0) / (x + 1.0);
  const double y2 = y * y;
  double t = y, s = 0.0;
  for (int i = 0; i < 40; ++i) { s += t / (double)(2 * i + 1); t *= y2; }
  return 2.0 * s + (double)k * 0.69314718055994530942;
}
constexpr double melf(double f) { return 1127.0 * cln(1.0 + f / 700.0); }

struct MelTab {
  int   kbe[NMEL];
  float w[NMEL][KN];
  constexpr MelTab() : kbe{}, w{} {
    const double mlo = melf(80.0), mhi = melf(7600.0);
    const double dm  = (mhi - mlo) / 81.0;
    for (int j = 0; j < NMEL; ++j) {
      const double lower = mlo + dm * (double)j;
      const double upper = lower + 2.0 * dm;
      int kb = 64;
      for (int k = 1; k < NBIN; ++k) {
        const double m = melf(125.0 * (double)k);
        const double a = m - lower, b2 = upper - m;
        if ((a < b2 ? a : b2) > 0.0) { kb = k; break; }
      }
      if (kb > NBIN - KN) kb = NBIN - KN;
      kbe[j] = kb;
      for (int r = 0; r < KN; ++r) {
        const int k = kb + r;
        double ww = 0.0;
        if (k >= 1 && k < NBIN) {
          const double m = melf(125.0 * (double)k);
          const double a = (m - lower) / dm, b2 = (upper - m) / dm;
          ww = a < b2 ? a : b2;
          if (ww < 0.0) ww = 0.0;
        }
        w[j][r] = (float)ww;
      }
    }
  }
};
constexpr MelTab MT{};

// 20 mel filters starting at J0 for one frame; indices/weights compile-time folded.
template <int J0>
__device__ __forceinline__ void mel20(const __half* mrow, float* srow) {
#pragma unroll
  for (int jj = 0; jj < 20; ++jj) {
    const int j = J0 + jj;
    float acc = 0.0f;
#pragma unroll
    for (int r = 0; r < KN; ++r) {
      if (MT.w[j][r] != 0.0f)          // constexpr -> folded branch
        acc = fmaf(MT.w[j][r], __half2float(mrow[MT.kbe[j] + r]), acc);
    }
    srow[1 + j] = acc;
  }
}

// ---------------- kernel ----------------
// Per block: 64 frames. DFT as GEMM A(64x128, Hankel of raw samples) x
// B(128x160 fp16: cols 0..64 = wh*cos, 80..144 = -wh*sin, rest pad).
// MFMA f32_16x16x32_f16, wave = M-tile. Re tile r and Im tile r+5 share
// lane layout -> magnitude is lane-local. B built on-device (no constexpr
// device table, no swizzle -- round-1 failure class eliminated).
__global__ __launch_bounds__(NTHR, 3) void melspec_kernel(const float* __restrict__ x,
                                                          float* __restrict__ out) {
  // bt (phases 0-1) and fp32 stage (phases 2-3) share this region (barrier-separated)
  __shared__ __align__(16) unsigned char smem[160 * BSTR * 2];  // 43520 B
  __shared__ float  xs[192];
  __shared__ __half magh[T_FR * MSTR];                          // 8960 B

  const int tid = threadIdx.x;
  const int t0  = blockIdx.x * T_FR;
  const int b   = blockIdx.y;

  // ---- phase 0a: input chunk (zero-pad past row end) ----
  const float* xrow = x + (size_t)b * N_SZ;
  if (tid < 192) xs[tid] = (t0 + tid < N_SZ) ? xrow[t0 + tid] : 0.0f;

  // ---- phase 0b: build windowed DFT coefficient table in LDS (fp16) ----
  {
    _Float16* bt = (_Float16*)smem;
    const float w0 = 6.2831853071795864769f / 128.0f;   // 2*pi/128
    for (int e = tid; e < NBIN * 128; e += NTHR) {
      const int k = e >> 7, n = e & 127;
      const float wh = 0.5f - 0.5f * __cosf(w0 * (float)n);   // Hann
      float sv, cv;
      __sincosf(w0 * (float)((k * n) & 127), &sv, &cv);       // exact angle mod 2pi
      bt[k * BSTR + n]        = (_Float16)(wh * cv);          // Re row
      bt[(80 + k) * BSTR + n] = (_Float16)(-wh * sv);         // Im row
    }
    for (int e = tid; e < 15 * 128; e += NTHR) {              // zero pad cols
      const int c = e >> 7, n = e & 127;
      bt[(65 + c) * BSTR + n]  = (_Float16)0.f;
      bt[(145 + c) * BSTR + n] = (_Float16)0.f;
    }
  }
  __syncthreads();

  // ---- phase 1: DFT via MFMA ----
  const int wv = tid >> 6;     // wave id = M-tile (frames 16*wv .. 16*wv+15)
  const int ln = tid & 63;
  const int lr = ln & 15;      // A row / B col / C col
  const int lg = ln >> 4;      // k-group

  f4 acc[10];
  {
    const f4 z = {0.f, 0.f, 0.f, 0.f};
#pragma unroll
    for (int i = 0; i < 10; ++i) acc[i] = z;
  }

  const _Float16* btp = (const _Float16*)smem;
#pragma unroll
  for (int kk = 0; kk < 4; ++kk) {
    // A fragment: A[m][k] = xs[16*wv + m + k]; lane: m=lr, k = kk*32 + lg*8 + j
    h8 a;
    const float* ap = xs + 16 * wv + lr + kk * 32 + lg * 8;
#pragma unroll
    for (int j = 0; j < 8; ++j) a[j] = (_Float16)ap[j];
    // B fragments for all 10 N-tiles: B[k][c] = bt[c*BSTR + k]
    h8 bfr[10];
#pragma unroll
    for (int nt = 0; nt < 10; ++nt)
      bfr[nt] = *(const h8*)(btp + (nt * 16 + lr) * BSTR + kk * 32 + lg * 8);
#pragma unroll
    for (int nt = 0; nt < 10; ++nt)
      acc[nt] = __builtin_amdgcn_mfma_f32_16x16x32_f16(a, bfr[nt], acc[nt], 0, 0, 0);
  }

  // ---- phase 1b: magnitude -> LDS fp16 (C/D: col=lane&15, row=(lane>>4)*4+reg) ----
#pragma unroll
  for (int r = 0; r < 5; ++r) {
    if (r < 4 || lr == 0) {                  // tile 4 only carries bin 64
      const int k = r * 16 + lr;
#pragma unroll
      for (int v = 0; v < 4; ++v) {
        const int t = 16 * wv + lg * 4 + v;
        const float re = acc[r][v], im = acc[r + 5][v];
        magh[t * MSTR + k] = __float2half(sqrtf(re * re + im * im));
      }
    }
  }
  __syncthreads();

  // ---- phase 2: sparse mel + fp32 stage (overlays bt region) ----
  float* stage = (float*)smem;
  {
    const int t = tid & 63, q = tid >> 6;    // wave-uniform q -> uniform branch
    const __half* mrow = magh + t * MSTR;
    float* srow = stage + t * NCH;
    if (q == 0) srow[0] = xs[t];             // channel 0 = x, exact fp32
    switch (q) {
      case 0:  mel20<0>(mrow, srow);  break;
      case 1:  mel20<20>(mrow, srow); break;
      case 2:  mel20<40>(mrow, srow); break;
      default: mel20<60>(mrow, srow); break;
    }
  }
  __syncthreads();

  // ---- phase 3: coalesced fp32 store (5184 floats per block) ----
  float* orow = out + ((size_t)b * N_SZ + t0) * NCH;
#pragma unroll
  for (int i = 0; i < 5; ++i) {
    const int f = i * 1024 + tid * 4;
    *(float4*)(orow + f) = *(const float4*)(stage + f);
  }
  if (tid < 64) orow[5120 + tid] = stage[5120 + tid];
}

extern "C" void kernel_launch(void* const* d_in, const int* in_sizes, int n_in,
                              void* d_out, int out_size, void* d_ws, size_t ws_size,
                              hipStream_t stream) {
  const float* x = (const float*)d_in[0];
  float* out = (float*)d_out;
  dim3 grid(N_SZ / T_FR, B_SZ);
  dim3 block(NTHR);
  hipLaunchKernelGGL(melspec_kernel, grid, block, 0, stream, x, out);
}

// Round 4
// 106.323 us; speedup vs baseline: 1.1291x; 1.1291x over previous
//
#include <hip/hip_runtime.h>
#include <hip/hip_fp16.h>
#include <math.h>

#define B_SZ 16
#define N_SZ 16384
#define T_FR 64       // frames per block
#define NTHR 256      // 4 waves
#define NMEL 80
#define NCH  81

typedef _Float16 h8  __attribute__((ext_vector_type(8)));
typedef _Float16 h4  __attribute__((ext_vector_type(4)));
typedef float    f4  __attribute__((ext_vector_type(4)));
static_assert(sizeof(h8) == 16, "h8 must be 4 VGPRs");

// Fragment-ordered coefficient tables, built each iteration by build_tables.
// Units 0..2047:   DFT A-frags: unit = ((g*2+pol)*4+kk)*64 + ln
//                  value[j] = coef[bin=16g+(ln&15)][k=kk*32+((ln>>4)&3)*8+j]
//                  pol0: wh[k]*cos(2pi*bin*k/128), pol1: -wh[k]*sin(...)
// Units 2048..2687: mel W^T A-frags: unit = 2048 + (jt*2+kkB)*64 + ln
//                  value[j] = W[bin=kkB*32+((ln>>4)&3)*8+j][melj=16jt+(ln&15)]
__device__ _Float16 g_tab[2688 * 8];

// ---------------- precompute kernel (runs once per launch, ~2 us) ----------------
__global__ void build_tables() {
  const int u = blockIdx.x * blockDim.x + threadIdx.x;
  if (u >= 2688) return;
  const float w0 = 6.2831853071795864769f / 128.0f;   // 2*pi/128
  h8 res;
  if (u < 2048) {
    const int ln = u & 63, kk = (u >> 6) & 3, pol = (u >> 8) & 1, g = u >> 9;
    const int bin = 16 * g + (ln & 15);
    const int k0  = kk * 32 + ((ln >> 4) & 3) * 8;
#pragma unroll
    for (int j = 0; j < 8; ++j) {
      const int k = k0 + j;
      const float wh = 0.5f - 0.5f * __cosf(w0 * (float)k);   // Hann
      float sv, cv;
      __sincosf(w0 * (float)((bin * k) & 127), &sv, &cv);     // exact angle mod 2pi
      res[j] = (_Float16)(pol ? (-wh * sv) : (wh * cv));
    }
  } else {
    const int u2 = u - 2048;
    const int ln = u2 & 63, kkB = (u2 >> 6) & 1, jt = u2 >> 7;
    const int mj = 16 * jt + (ln & 15);
    const int b0 = kkB * 32 + ((ln >> 4) & 3) * 8;
    const float mlo = 1127.0f * logf(1.0f + 80.0f / 700.0f);
    const float mhi = 1127.0f * logf(1.0f + 7600.0f / 700.0f);
    const float dm  = (mhi - mlo) / 81.0f;
#pragma unroll
    for (int j = 0; j < 8; ++j) {
      const int bin = b0 + j;                                  // 0..63
      const float m  = 1127.0f * logf(1.0f + 125.0f * (float)bin / 700.0f);
      const float lower = mlo + dm * (float)mj;
      const float ls = (m - lower) / dm;                       // bin0: ls<0 -> w=0
      const float us = (lower + 2.0f * dm - m) / dm;
      res[j] = (_Float16)fmaxf(0.0f, fminf(ls, us));
    }
  }
  ((h8*)g_tab)[u] = res;
}

// ---------------- main kernel ----------------
// 64 frames/block, 4 waves. Phase 1: DFT C[bin][frame] via MFMA with stationary
// coef A-frags (VGPR, from g_tab) and Hankel x B-frags (1 ds_read_b128 each).
// Wave = 16-bin group (bins 0..63; bins 0 & 64 have zero mel weight -> dropped).
// Re/Im accs share lane layout -> magnitude lane-local, packed b64 into magT in
// mel-B fragment order. Phase 2: mel C[melj][frame] via MFMA, K=64, stationary
// W^T A-frags. Phase 3: LDS stage -> coalesced float4 stores.
__global__ __launch_bounds__(NTHR) void melspec_kernel(const float* __restrict__ x,
                                                       float* __restrict__ out) {
  __shared__ __align__(16) _Float16 xh2[184 * 8];   // Hankel: unit n = x[n..n+7]
  __shared__ __align__(16) _Float16 magT[512 * 8];  // unit bg*64+frame, half = bin&7
  __shared__ float xs[64];                          // exact fp32 x for channel 0
  __shared__ __align__(16) float stage[T_FR * NCH]; // 5184 f32, output layout
  // total 32128 B -> 5 blocks/CU

  const int tid = threadIdx.x;
  const int t0  = blockIdx.x * T_FR;
  const int b   = blockIdx.y;
  const float* xrow = x + (size_t)b * N_SZ;

  const int wv = tid >> 6;       // wave id
  const int ln = tid & 63;
  const int lr = ln & 15;        // A-row / B-col / C-col
  const int lg = (ln >> 4) & 3;  // k-subgroup

  // ---- phase 0: Hankel x table (fp16) + exact-x row; stationary DFT A-frags ----
  if (tid < 64) xs[tid] = xrow[t0 + tid];           // t0+63 < N_SZ always
  if (tid < 184) {
    h8 tmp;
#pragma unroll
    for (int j = 0; j < 8; ++j) {
      const int gix = t0 + tid + j;
      tmp[j] = (_Float16)((gix < N_SZ) ? xrow[gix] : 0.0f);   // zero-pad tail
    }
    *(h8*)(xh2 + tid * 8) = tmp;
  }
  const h8* tabv = (const h8*)g_tab;
  h8 aRe[4], aIm[4];
#pragma unroll
  for (int kk = 0; kk < 4; ++kk) {
    aRe[kk] = tabv[((wv * 2 + 0) * 4 + kk) * 64 + ln];
    aIm[kk] = tabv[((wv * 2 + 1) * 4 + kk) * 64 + ln];
  }
  __syncthreads();

  // ---- phase 1: DFT + magnitude ----
#pragma unroll
  for (int ft = 0; ft < 4; ++ft) {
    f4 cr = {0.f, 0.f, 0.f, 0.f};
    f4 ci = {0.f, 0.f, 0.f, 0.f};
#pragma unroll
    for (int kk = 0; kk < 4; ++kk) {
      // B[k][col=lr] = x[(16ft+lr) + k], k = kk*32+lg*8+j -> Hankel unit
      const h8 bb = *(const h8*)(xh2 + (16 * ft + 32 * kk + 8 * lg + lr) * 8);
      cr = __builtin_amdgcn_mfma_f32_16x16x32_f16(aRe[kk], bb, cr, 0, 0, 0);
      ci = __builtin_amdgcn_mfma_f32_16x16x32_f16(aIm[kk], bb, ci, 0, 0, 0);
    }
    // C: col=lr=frame-in-ft, row=4*lg+v = bin-in-group -> bin = 16wv+4lg+v
    h4 pk;
#pragma unroll
    for (int v = 0; v < 4; ++v) {
      const float re = cr[v], im = ci[v];
      pk[v] = (_Float16)sqrtf(re * re + im * im);
    }
    const int bg = 2 * wv + (lg >> 1);               // bin>>3
    *(h4*)(magT + ((bg * 64 + 16 * ft + lr) * 8 + 4 * (lg & 1))) = pk;  // half=bin&7
  }
  // stationary mel A-frags (issue before barrier; latency hides under the wait)
  h8 aW[10];
#pragma unroll
  for (int q = 0; q < 10; ++q) aW[q] = tabv[2048 + q * 64 + ln];  // q = jt*2+kkB
  __syncthreads();

  // ---- phase 2: mel GEMM (K=64) + stage ----
  f4 acc[5];
  {
    const f4 z = {0.f, 0.f, 0.f, 0.f};
#pragma unroll
    for (int i = 0; i < 5; ++i) acc[i] = z;
  }
#pragma unroll
  for (int kkB = 0; kkB < 2; ++kkB) {
    // B[bin][col=lr] = magT, frame = 16wv + lr, bin-slice = kkB*32+lg*8+j
    const h8 bb = *(const h8*)(magT + ((kkB * 4 + lg) * 64 + 16 * wv + lr) * 8);
#pragma unroll
    for (int jt = 0; jt < 5; ++jt)
      acc[jt] = __builtin_amdgcn_mfma_f32_16x16x32_f16(aW[jt * 2 + kkB], bb, acc[jt], 0, 0, 0);
  }
  {
    const int fr = 16 * wv + lr;                     // wave's frame quarter
    float* srow = stage + fr * NCH;
    if (lg == 0) srow[0] = xs[fr];                   // channel 0 = exact x
#pragma unroll
    for (int jt = 0; jt < 5; ++jt)
#pragma unroll
      for (int v = 0; v < 4; ++v)
        srow[1 + 16 * jt + 4 * lg + v] = acc[jt][v]; // melj = 16jt+4lg+v
  }
  __syncthreads();

  // ---- phase 3: coalesced fp32 store (5184 floats) ----
  float* orow = out + ((size_t)b * N_SZ + t0) * NCH;
#pragma unroll
  for (int i = 0; i < 5; ++i) {
    const int f = i * 1024 + tid * 4;
    *(float4*)(orow + f) = *(const float4*)(stage + f);
  }
  if (tid < 64) orow[5120 + tid] = stage[5120 + tid];
}

extern "C" void kernel_launch(void* const* d_in, const int* in_sizes, int n_in,
                              void* d_out, int out_size, void* d_ws, size_t ws_size,
                              hipStream_t stream) {
  const float* x = (const float*)d_in[0];
  float* out = (float*)d_out;
  hipLaunchKernelGGL(build_tables, dim3(11), dim3(256), 0, stream);
  dim3 grid(N_SZ / T_FR, B_SZ);
  dim3 block(NTHR);
  hipLaunchKernelGGL(melspec_kernel, grid, block, 0, stream, x, out);
}

// Round 5
// 102.326 us; speedup vs baseline: 1.1732x; 1.0391x over previous
//
#include <hip/hip_runtime.h>
#include <hip/hip_fp16.h>
#include <math.h>

#define B_SZ 16
#define N_SZ 16384
#define T_FR 128      // frames per block
#define NTHR 256      // 4 waves
#define NMEL 80
#define NCH  81
#define MAGS 129      // magT row stride in 16B units (odd -> bank-group spread)

typedef _Float16 h8  __attribute__((ext_vector_type(8)));
typedef _Float16 h4  __attribute__((ext_vector_type(4)));
typedef float    f4  __attribute__((ext_vector_type(4)));
static_assert(sizeof(h8) == 16, "h8 must be 4 VGPRs");

// Fragment-ordered coefficient tables, built each iteration by build_tables.
// Units 0..2047:   DFT A-frags: unit = ((g*2+pol)*4+kk)*64 + ln
//                  value[j] = coef[bin=16g+(ln&15)][k=kk*32+((ln>>4)&3)*8+j]
//                  pol0: wh[k]*cos(2pi*bin*k/128), pol1: -wh[k]*sin(...)
// Units 2048..2687: mel W^T A-frags: unit = 2048 + (jt*2+kkB)*64 + ln
//                  value[j] = W[bin=kkB*32+((ln>>4)&3)*8+j][melj=16jt+(ln&15)]
__device__ _Float16 g_tab[2688 * 8];

// ---------------- precompute kernel (~2 us, 11 blocks) ----------------
__global__ void build_tables() {
  const int u = blockIdx.x * blockDim.x + threadIdx.x;
  if (u >= 2688) return;
  const float w0 = 6.2831853071795864769f / 128.0f;   // 2*pi/128
  h8 res;
  if (u < 2048) {
    const int ln = u & 63, kk = (u >> 6) & 3, pol = (u >> 8) & 1, g = u >> 9;
    const int bin = 16 * g + (ln & 15);
    const int k0  = kk * 32 + ((ln >> 4) & 3) * 8;
#pragma unroll
    for (int j = 0; j < 8; ++j) {
      const int k = k0 + j;
      const float wh = 0.5f - 0.5f * __cosf(w0 * (float)k);   // Hann
      float sv, cv;
      __sincosf(w0 * (float)((bin * k) & 127), &sv, &cv);     // exact angle mod 2pi
      res[j] = (_Float16)(pol ? (-wh * sv) : (wh * cv));
    }
  } else {
    const int u2 = u - 2048;
    const int ln = u2 & 63, kkB = (u2 >> 6) & 1, jt = u2 >> 7;
    const int mj = 16 * jt + (ln & 15);
    const int b0 = kkB * 32 + ((ln >> 4) & 3) * 8;
    const float mlo = 1127.0f * logf(1.0f + 80.0f / 700.0f);
    const float mhi = 1127.0f * logf(1.0f + 7600.0f / 700.0f);
    const float dm  = (mhi - mlo) / 81.0f;
#pragma unroll
    for (int j = 0; j < 8; ++j) {
      const int bin = b0 + j;                                  // 0..63
      const float m  = 1127.0f * logf(1.0f + 125.0f * (float)bin / 700.0f);
      const float lower = mlo + dm * (float)mj;
      const float ls = (m - lower) / dm;                       // bin0 -> w=0
      const float us = (lower + 2.0f * dm - m) / dm;
      res[j] = (_Float16)fmaxf(0.0f, fminf(ls, us));
    }
  }
  ((h8*)g_tab)[u] = res;
}

// ---------------- main kernel ----------------
// 128 frames/block, 4 waves. Wave owns bin group 16wv..16wv+15 in phase 1
// (all 128 frames, 64 MFMA) and frame groups {wv, wv+4} in phase 2 (all 80
// mels). Phase 2+3 are wave-local: stage slice + stores need no barrier,
// only an in-wave lgkmcnt drain. Mappings identical to the validated r4.
__global__ __launch_bounds__(NTHR) void melspec_kernel(const float* __restrict__ x,
                                                       float* __restrict__ out) {
  __shared__ __align__(16) _Float16 xh2[248 * 8];        // Hankel: unit n = x[n..n+7]
  __shared__ __align__(16) _Float16 magT[8 * MAGS * 8];  // bg-major, 129-unit rows
  __shared__ float xs[T_FR];                             // exact fp32 x (channel 0)
  __shared__ __align__(16) float stage[4][1296];         // per-wave 16x81 slice
  // total 41728 B -> 3 blocks/CU

  const int tid = threadIdx.x;
  const int t0  = blockIdx.x * T_FR;
  const int b   = blockIdx.y;
  const float* xrow = x + (size_t)b * N_SZ;

  const int wv = tid >> 6;       // wave id
  const int ln = tid & 63;
  const int lr = ln & 15;        // A-row / B-col / C-col
  const int lg = (ln >> 4) & 3;  // k-subgroup

  // ---- phase 0: x -> xs (float4), Hankel fp16 units, stationary DFT A-frags ----
  if (tid < T_FR / 4)
    ((float4*)xs)[tid] = ((const float4*)(xrow + t0))[tid];  // t0+127 < N_SZ always
  if (tid < 248) {               // units 0..247 cover frame 127 + k 127
    h8 tmp;
#pragma unroll
    for (int j = 0; j < 8; ++j) {
      const int gix = t0 + tid + j;
      tmp[j] = (_Float16)((gix < N_SZ) ? xrow[gix] : 0.0f);  // zero-pad row tail
    }
    *(h8*)(xh2 + tid * 8) = tmp;
  }
  const h8* tabv = (const h8*)g_tab;
  h8 aRe[4], aIm[4];
#pragma unroll
  for (int kk = 0; kk < 4; ++kk) {
    aRe[kk] = tabv[((wv * 2 + 0) * 4 + kk) * 64 + ln];
    aIm[kk] = tabv[((wv * 2 + 1) * 4 + kk) * 64 + ln];
  }
  __syncthreads();

  // ---- phase 1: DFT + magnitude, all 128 frames of this wave's 16 bins ----
#pragma unroll
  for (int ft = 0; ft < 8; ++ft) {
    f4 cr = {0.f, 0.f, 0.f, 0.f};
    f4 ci = {0.f, 0.f, 0.f, 0.f};
#pragma unroll
    for (int kk = 0; kk < 4; ++kk) {
      // B[k][col=lr] = x[(16ft+lr) + k], k = kk*32+lg*8+j -> Hankel unit
      const h8 bb = *(const h8*)(xh2 + (16 * ft + 32 * kk + 8 * lg + lr) * 8);
      cr = __builtin_amdgcn_mfma_f32_16x16x32_f16(aRe[kk], bb, cr, 0, 0, 0);
      ci = __builtin_amdgcn_mfma_f32_16x16x32_f16(aIm[kk], bb, ci, 0, 0, 0);
    }
    // C: col=lr=frame-in-ft, row=4lg+v=bin-in-group; bin = 16wv+4lg+v
    h4 pk;
#pragma unroll
    for (int v = 0; v < 4; ++v) {
      const float re = cr[v], im = ci[v];
      pk[v] = (_Float16)sqrtf(re * re + im * im);
    }
    const int bg = 2 * wv + (lg >> 1);                       // bin>>3
    *(h4*)(magT + ((bg * MAGS + 16 * ft + lr) * 8 + 4 * (lg & 1))) = pk;
  }
  // stationary mel A-frags (issued before the barrier; latency hides in the wait)
  h8 aW[10];
#pragma unroll
  for (int q = 0; q < 10; ++q) aW[q] = tabv[2048 + q * 64 + ln];  // q = jt*2+kkB
  __syncthreads();

  // ---- phase 2+3: per wave, two 16-frame groups; mel GEMM -> stage -> store ----
  float* orow = out + ((size_t)b * N_SZ + t0) * NCH;
#pragma unroll
  for (int gi = 0; gi < 2; ++gi) {
    const int g = wv + 4 * gi;                               // frame group 16g..16g+15
    f4 acc[5];
    {
      const f4 z = {0.f, 0.f, 0.f, 0.f};
#pragma unroll
      for (int i = 0; i < 5; ++i) acc[i] = z;
    }
#pragma unroll
    for (int kkB = 0; kkB < 2; ++kkB) {
      // B[bin][col=lr]: frame = 16g+lr, bin-slice = kkB*32+lg*8+j -> row kkB*4+lg
      const h8 bb = *(const h8*)(magT + ((kkB * 4 + lg) * MAGS + 16 * g + lr) * 8);
#pragma unroll
      for (int jt = 0; jt < 5; ++jt)
        acc[jt] = __builtin_amdgcn_mfma_f32_16x16x32_f16(aW[jt * 2 + kkB], bb, acc[jt], 0, 0, 0);
    }
    {
      float* srow = stage[wv] + lr * NCH;                    // wave-local slice
      if (lg == 0) srow[0] = xs[16 * g + lr];                // channel 0 = exact x
#pragma unroll
      for (int jt = 0; jt < 5; ++jt)
#pragma unroll
        for (int v = 0; v < 4; ++v)
          srow[1 + 16 * jt + 4 * lg + v] = acc[jt][v];       // melj = 16jt+4lg+v
    }
    // in-wave cross-lane LDS RAW: drain DS pipe (no block barrier needed)
    __asm volatile("s_waitcnt lgkmcnt(0)" ::: "memory");
    // coalesced store of this wave's 1296-float slice (324 float4)
    float* obase = orow + (size_t)(16 * g) * NCH;
    const float* sl = stage[wv];
#pragma unroll
    for (int i = 0; i < 5; ++i) {
      const int f = (i * 64 + ln) * 4;
      *(float4*)(obase + f) = *(const float4*)(sl + f);
    }
    if (ln < 4) {
      const int f = (320 + ln) * 4;
      *(float4*)(obase + f) = *(const float4*)(sl + f);
    }
  }
}

extern "C" void kernel_launch(void* const* d_in, const int* in_sizes, int n_in,
                              void* d_out, int out_size, void* d_ws, size_t ws_size,
                              hipStream_t stream) {
  const float* x = (const float*)d_in[0];
  float* out = (float*)d_out;
  hipLaunchKernelGGL(build_tables, dim3(11), dim3(256), 0, stream);
  dim3 grid(N_SZ / T_FR, B_SZ);
  dim3 block(NTHR);
  hipLaunchKernelGGL(melspec_kernel, grid, block, 0, stream, x, out);
}